// Round 5
// baseline (2993.080 us; speedup 1.0000x reference)
//
#include <hip/hip_runtime.h>
#include <hip/hip_bf16.h>

// ---------------- constants ----------------
constexpr int CB   = 2;     // batch
constexpr int CS   = 2048;  // seq
constexpr int CH   = 2048;  // hidden
constexpr int CNH  = 16;    // heads
constexpr int CHD  = 128;   // head dim
constexpr int CE   = 8;     // experts
constexpr int CI   = 2048;  // ffn inner
constexpr int CT   = CB * CS;      // 4096 tokens
constexpr int CQKV = 3 * CH;       // 6144

typedef __attribute__((ext_vector_type(8))) short short8;
typedef __attribute__((ext_vector_type(4))) float float4v;
typedef __attribute__((ext_vector_type(4))) unsigned short ushort4v;
typedef unsigned int uint32;

__device__ __forceinline__ float bf2f(unsigned short u) {
    union { unsigned int i; float f; } x; x.i = ((unsigned int)u) << 16; return x.f;
}
__device__ __forceinline__ unsigned short f2bf(float f) {
    union { float f; unsigned int i; } x; x.f = f;
    unsigned int r = x.i + 0x7fffu + ((x.i >> 16) & 1u);
    return (unsigned short)(r >> 16);
}
__device__ __forceinline__ uint32 packpair(uint32 r0, uint32 r1) {
    return __builtin_amdgcn_perm(r1, r0, 0x07060302u);
}
__device__ __forceinline__ uint32 rnebits(float f) {
    uint32 u = __float_as_uint(f);
    return u + 0x7fffu + ((u >> 16) & 1u);
}
__device__ __forceinline__ void split2(float f0, float f1, uint32& h, uint32& l) {
    uint32 r0 = rnebits(f0), r1 = rnebits(f1);
    h = packpair(r0, r1);
    float d0 = f0 - __uint_as_float(r0 & 0xffff0000u);
    float d1 = f1 - __uint_as_float(r1 & 0xffff0000u);
    l = packpair(rnebits(d0), rnebits(d1));
}
__device__ __forceinline__ void rne16_store(const float* fv, unsigned short* dst) {
    uint32 h[8];
    #pragma unroll
    for (int p = 0; p < 8; p++) h[p] = packpair(rnebits(fv[2 * p]), rnebits(fv[2 * p + 1]));
    ((uint4*)dst)[0] = make_uint4(h[0], h[1], h[2], h[3]);
    ((uint4*)dst)[1] = make_uint4(h[4], h[5], h[6], h[7]);
}

// ---------------- RMSNorm. MODE 0: hi/lo split out. MODE 1: bf16 out ----------
template<int MODE>
__global__ __launch_bounds__(256) void rmsnorm_k(const float* __restrict__ x,
                                                 const float* __restrict__ w,
                                                 unsigned short* __restrict__ o1,
                                                 unsigned short* __restrict__ o2) {
    const int row = blockIdx.x;
    const float* xr = x + (size_t)row * CH;
    const int base = threadIdx.x * 8;
    float4 v0 = *(const float4*)(xr + base);
    float4 v1 = *(const float4*)(xr + base + 4);
    float ss = v0.x*v0.x + v0.y*v0.y + v0.z*v0.z + v0.w*v0.w
             + v1.x*v1.x + v1.y*v1.y + v1.z*v1.z + v1.w*v1.w;
    #pragma unroll
    for (int o = 1; o < 64; o <<= 1) ss += __shfl_xor(ss, o);
    __shared__ float ps[4];
    if ((threadIdx.x & 63) == 0) ps[threadIdx.x >> 6] = ss;
    __syncthreads();
    const float scale = rsqrtf((ps[0] + ps[1] + ps[2] + ps[3]) / (float)CH + 1e-5f);
    float4 w0 = *(const float4*)(w + base);
    float4 w1 = *(const float4*)(w + base + 4);
    float r[8] = {v0.x * scale * w0.x, v0.y * scale * w0.y, v0.z * scale * w0.z, v0.w * scale * w0.w,
                  v1.x * scale * w1.x, v1.y * scale * w1.y, v1.z * scale * w1.z, v1.w * scale * w1.w};
    if (MODE == 1) {
        rne16_store(r, o1 + (size_t)row * CH + base);
    } else {
        uint32 h[4], l[4];
        #pragma unroll
        for (int p = 0; p < 4; p++) split2(r[2 * p], r[2 * p + 1], h[p], l[p]);
        *(uint4*)(o1 + (size_t)row * CH + base) = make_uint4(h[0], h[1], h[2], h[3]);
        *(uint4*)(o2 + (size_t)row * CH + base) = make_uint4(l[0], l[1], l[2], l[3]);
    }
}

// ---------------- RoPE table (replicating np's fp32 rounding) ----
__global__ void rope_tab_k(float2* __restrict__ tab) {
    int i = blockIdx.x * 256 + threadIdx.x;   // 2048*64
    int p = i >> 6, j = i & 63;
    double inv = pow(10000.0, -(double)j / 64.0);
    float invf = (float)inv;
    float angf = (float)p * invf;
    double da = (double)angf;
    tab[i] = make_float2((float)cos(da), (float)sin(da));
}

// ---------------- RoPE (in-place on hi/lo split q,k) ----------------
__global__ __launch_bounds__(256) void rope_k(unsigned short* __restrict__ qh,
                                              unsigned short* __restrict__ ql,
                                              const int* __restrict__ pos,
                                              const float2* __restrict__ tab) {
    int i = blockIdx.x * 256 + threadIdx.x;  // CT*16*64
    if (i >= CT * CNH * 64) return;
    int t = i >> 10, hj = i & 1023, hh = hj >> 6, j = hj & 63;
    float2 cs = tab[(size_t)pos[t] * 64 + j];
    unsigned short* qhp = qh + (size_t)t * CQKV + hh * CHD;
    unsigned short* qlp = ql + (size_t)t * CQKV + hh * CHD;
    #pragma unroll
    for (int s = 0; s < 2; s++) {
        unsigned short* hp = qhp + s * CH;   // q then k
        unsigned short* lp = qlp + s * CH;
        float x1 = bf2f(hp[j]) + bf2f(lp[j]);
        float x2 = bf2f(hp[j + 64]) + bf2f(lp[j + 64]);
        float y1 = x1 * cs.x - x2 * cs.y;
        float y2 = x2 * cs.x + x1 * cs.y;
        uint32 r1 = rnebits(y1), r2 = rnebits(y2);
        hp[j]      = (unsigned short)(r1 >> 16);
        hp[j + 64] = (unsigned short)(r2 >> 16);
        lp[j]      = f2bf(y1 - __uint_as_float(r1 & 0xffff0000u));
        lp[j + 64] = f2bf(y2 - __uint_as_float(r2 & 0xffff0000u));
    }
}

// ---------------- precise split-bf16 GEMM: A split-bf16, B fp32 ----------------
// Register-prefetch pipelined. Grid: x = mt (row tiles), y = nt (col tiles).
// MODE 0: QKV — B from (q_w,k_w,v_w) by nt>>4, out split hi/lo bf16
// MODE 1: C f32 = A@B + resid, dual-store C2
template<int MODE>
__global__ __launch_bounds__(256) void pgemm_k(
    const unsigned short* __restrict__ Ahg, const unsigned short* __restrict__ Alg, int lda,
    const float* __restrict__ B0, const float* __restrict__ B1, const float* __restrict__ B2,
    int ldb, int K,
    unsigned short* __restrict__ Ch, unsigned short* __restrict__ Cl,
    float* __restrict__ Cf, int ldc,
    const float* __restrict__ resid, float* __restrict__ C2) {
    __shared__ unsigned short Ah[128][40], Al[128][40];
    __shared__ unsigned short Bh[128][40], Bl[128][40];
    const int mt = blockIdx.x, nt = blockIdx.y, tid = threadIdx.x;
    const int m0 = mt * 128;
    const int arow = tid >> 1, acol = tid & 1;
    const unsigned short* ah_src = Ahg + (size_t)(m0 + arow) * lda + acol * 16;
    const unsigned short* al_src = Alg + (size_t)(m0 + arow) * lda + acol * 16;
    const float* src = B0; int col0 = nt * 128;
    if (MODE == 0) { int w = nt >> 4; src = (w == 0) ? B0 : ((w == 1) ? B1 : B2); col0 = (nt & 15) * 128; }
    const int bc_ = tid & 127, bhalf = tid >> 7;
    const float* bcol = src + col0 + bc_;   // column strip, row stride = ldb
    const int lane = tid & 63, lr = lane & 15, lg = lane >> 4;
    const int wr = (tid >> 7) & 1, wc = (tid >> 6) & 1;

    float4v acc[4][4];
    #pragma unroll
    for (int m = 0; m < 4; m++)
        #pragma unroll
        for (int n = 0; n < 4; n++) acc[m][n] = (float4v){0.f, 0.f, 0.f, 0.f};

    // prefetch k0 = 0
    short8 pah0 = *(const short8*)(ah_src);
    short8 pah1 = *(const short8*)(ah_src + 8);
    short8 pal0 = *(const short8*)(al_src);
    short8 pal1 = *(const short8*)(al_src + 8);
    float bv[16];
    {
        const float* bp = bcol + (size_t)(bhalf * 16) * ldb;
        #pragma unroll
        for (int j = 0; j < 16; j++) bv[j] = bp[(size_t)j * ldb];
    }

    for (int k0 = 0; k0 < K; k0 += 32) {
        __syncthreads();
        *(short8*)(&Ah[arow][acol * 16]) = pah0;
        *(short8*)(&Ah[arow][acol * 16 + 8]) = pah1;
        *(short8*)(&Al[arow][acol * 16]) = pal0;
        *(short8*)(&Al[arow][acol * 16 + 8]) = pal1;
        {   // split B regs -> LDS
            uint32 h[8], l[8];
            #pragma unroll
            for (int p = 0; p < 8; p++) split2(bv[2 * p], bv[2 * p + 1], h[p], l[p]);
            ((uint4*)&Bh[bc_][bhalf * 16])[0] = make_uint4(h[0], h[1], h[2], h[3]);
            ((uint4*)&Bh[bc_][bhalf * 16])[1] = make_uint4(h[4], h[5], h[6], h[7]);
            ((uint4*)&Bl[bc_][bhalf * 16])[0] = make_uint4(l[0], l[1], l[2], l[3]);
            ((uint4*)&Bl[bc_][bhalf * 16])[1] = make_uint4(l[4], l[5], l[6], l[7]);
        }
        if (k0 + 32 < K) {   // prefetch next tile (latency hides under MFMA phase)
            pah0 = *(const short8*)(ah_src + k0 + 32);
            pah1 = *(const short8*)(ah_src + k0 + 40);
            pal0 = *(const short8*)(al_src + k0 + 32);
            pal1 = *(const short8*)(al_src + k0 + 40);
            const float* bp = bcol + (size_t)(k0 + 32 + bhalf * 16) * ldb;
            #pragma unroll
            for (int j = 0; j < 16; j++) bv[j] = bp[(size_t)j * ldb];
        }
        __syncthreads();
        short8 fah[4], fal[4], fbh[4], fbl[4];
        #pragma unroll
        for (int m = 0; m < 4; m++) {
            fah[m] = *(const short8*)(&Ah[wr * 64 + m * 16 + lr][lg * 8]);
            fal[m] = *(const short8*)(&Al[wr * 64 + m * 16 + lr][lg * 8]);
        }
        #pragma unroll
        for (int n = 0; n < 4; n++) {
            fbh[n] = *(const short8*)(&Bh[wc * 64 + n * 16 + lr][lg * 8]);
            fbl[n] = *(const short8*)(&Bl[wc * 64 + n * 16 + lr][lg * 8]);
        }
        #pragma unroll
        for (int n = 0; n < 4; n++)
            #pragma unroll
            for (int m = 0; m < 4; m++) {
                acc[m][n] = __builtin_amdgcn_mfma_f32_16x16x32_bf16(fal[m], fbh[n], acc[m][n], 0, 0, 0);
                acc[m][n] = __builtin_amdgcn_mfma_f32_16x16x32_bf16(fah[m], fbl[n], acc[m][n], 0, 0, 0);
                acc[m][n] = __builtin_amdgcn_mfma_f32_16x16x32_bf16(fah[m], fbh[n], acc[m][n], 0, 0, 0);
            }
    }
    #pragma unroll
    for (int m = 0; m < 4; m++) {
        const int rb = wr * 64 + m * 16 + lg * 4;
        #pragma unroll
        for (int n = 0; n < 4; n++) {
            const int ccol = nt * 128 + wc * 64 + n * 16 + lr;
            #pragma unroll
            for (int r = 0; r < 4; r++) {
                const size_t idx = (size_t)(m0 + rb + r) * ldc + ccol;
                if (MODE == 1) {
                    const float v = acc[m][n][r] + resid[idx];
                    Cf[idx] = v;
                    C2[idx] = v;
                } else {
                    const float v = acc[m][n][r];
                    uint32 rr = rnebits(v);
                    Ch[idx] = (unsigned short)(rr >> 16);
                    Cl[idx] = f2bf(v - __uint_as_float(rr & 0xffff0000u));
                }
            }
        }
    }
}

// ---------------- fast bf16 GEMM for MoE (pipelined, grid x=mt) ----------
// MODE 2: up: A gathered by token list, B cols interleaved (w1,w3), SwiGLU -> bf16 H
// MODE 3: down: A = Hbuf rows, epilogue gate*val atomicAdd into out
template<int MODE>
__global__ __launch_bounds__(256) void gemm_k(
    const unsigned short* __restrict__ A, int lda,
    const float* __restrict__ B0, const float* __restrict__ B1,
    int ldb, int K, void* __restrict__ Cp, int ldc,
    const int* __restrict__ cnt, const int* __restrict__ tokl,
    const float* __restrict__ gatel, const int* __restrict__ pb) {
    __shared__ unsigned short As[128][40];
    __shared__ unsigned short Bt[128][40];
    const int mt = blockIdx.x, nt = blockIdx.y;
    const int m0 = mt * 128;
    const int e = blockIdx.z;
    const int c = cnt[e];
    if (m0 >= c) return;
    const int valid = (c - m0 < 128) ? (c - m0) : 128;
    const int tid = threadIdx.x;

    const unsigned short* a_src;
    {
        const int row = tid >> 1;
        size_t gr;
        if (MODE == 2) {
            int idx = m0 + (row < valid ? row : valid - 1);
            gr = (size_t)tokl[e * 4096 + idx];
        } else {
            gr = (size_t)(pb[e] + m0 + row);
        }
        a_src = A + gr * (size_t)lda + (tid & 1) * 16;
    }
    const int bc_ = tid & 127, bhalf = tid >> 7;
    const float* bcol;
    if (MODE == 2) {
        const float* mat = (bc_ & 1) ? B1 : B0;
        bcol = mat + (size_t)e * CH * CI + nt * 64 + (bc_ >> 1);
    } else {
        bcol = B0 + (size_t)e * (size_t)K * ldb + nt * 128 + bc_;
    }
    const int lane = tid & 63, lr = lane & 15, lg = lane >> 4;
    const int wr = (tid >> 7) & 1, wc = (tid >> 6) & 1;

    float4v acc[4][4];
    #pragma unroll
    for (int m = 0; m < 4; m++)
        #pragma unroll
        for (int n = 0; n < 4; n++) acc[m][n] = (float4v){0.f, 0.f, 0.f, 0.f};

    short8 pa0 = *(const short8*)(a_src);
    short8 pa1 = *(const short8*)(a_src + 8);
    float bv[16];
    {
        const float* bp = bcol + (size_t)(bhalf * 16) * ldb;
        #pragma unroll
        for (int j = 0; j < 16; j++) bv[j] = bp[(size_t)j * ldb];
    }

    for (int k0 = 0; k0 < K; k0 += 32) {
        __syncthreads();
        *(short8*)(&As[tid >> 1][(tid & 1) * 16]) = pa0;
        *(short8*)(&As[tid >> 1][(tid & 1) * 16 + 8]) = pa1;
        rne16_store(bv, &Bt[bc_][bhalf * 16]);
        if (k0 + 32 < K) {
            pa0 = *(const short8*)(a_src + k0 + 32);
            pa1 = *(const short8*)(a_src + k0 + 40);
            const float* bp = bcol + (size_t)(k0 + 32 + bhalf * 16) * ldb;
            #pragma unroll
            for (int j = 0; j < 16; j++) bv[j] = bp[(size_t)j * ldb];
        }
        __syncthreads();
        short8 af[4], bf[4];
        #pragma unroll
        for (int m = 0; m < 4; m++) af[m] = *(const short8*)(&As[wr * 64 + m * 16 + lr][lg * 8]);
        #pragma unroll
        for (int n = 0; n < 4; n++) bf[n] = *(const short8*)(&Bt[wc * 64 + n * 16 + lr][lg * 8]);
        #pragma unroll
        for (int n = 0; n < 4; n++)
            #pragma unroll
            for (int m = 0; m < 4; m++)
                acc[m][n] = __builtin_amdgcn_mfma_f32_16x16x32_bf16(af[m], bf[n], acc[m][n], 0, 0, 0);
    }

    #pragma unroll
    for (int m = 0; m < 4; m++) {
        const int rb = wr * 64 + m * 16 + lg * 4;
        #pragma unroll
        for (int n = 0; n < 4; n++) {
            const int col = nt * 128 + wc * 64 + n * 16 + lr;
            #pragma unroll
            for (int r = 0; r < 4; r++) {
                const int row = rb + r;
                const float v = acc[m][n][r];
                if (MODE == 2) {
                    const float other = __shfl_xor(v, 1);
                    if (!(lr & 1) && row < valid) {
                        const float g1 = v, g3 = other;
                        const float hsw = (g1 / (1.f + __expf(-g1))) * g3;
                        ((unsigned short*)Cp)[(size_t)(pb[e] + m0 + row) * ldc + (col >> 1)] = f2bf(hsw);
                    }
                } else {
                    if (row < valid) {
                        const int t = tokl[e * 4096 + m0 + row];
                        const float g = gatel[e * 4096 + m0 + row];
                        atomicAdd(((float*)Cp) + (size_t)t * ldc + col, v * g);
                    }
                }
            }
        }
    }
}

// ---------------- flash attention, split-bf16 in/out ----------
__global__ __launch_bounds__(256) void attn_k(const unsigned short* __restrict__ qh,
                                              const unsigned short* __restrict__ ql,
                                              unsigned short* __restrict__ ch,
                                              unsigned short* __restrict__ cl) {
    __shared__ unsigned short Ksh[32][136], Ksl[32][136];
    __shared__ unsigned short Vth[128][40], Vtl[128][40];
    const int qb = blockIdx.x;
    const int h  = blockIdx.y;
    const int b  = blockIdx.z;
    const int tid = threadIdx.x;
    const int wave = tid >> 6, lane = tid & 63, lr = lane & 15, lg = lane >> 4;
    const size_t tb = (size_t)b * CS;
    const int q0 = qb * 64 + wave * 16;

    short8 qfh[4], qfl[4];
    {
        const size_t off = (tb + q0 + lr) * CQKV + h * CHD;
        #pragma unroll
        for (int c = 0; c < 4; c++) {
            qfh[c] = *(const short8*)(qh + off + c * 32 + lg * 8);
            qfl[c] = *(const short8*)(ql + off + c * 32 + lg * 8);
        }
    }
    float4v o[8];
    #pragma unroll
    for (int d = 0; d < 8; d++) o[d] = (float4v){0.f, 0.f, 0.f, 0.f};
    float m = -1e30f, l = 0.f;
    const float scl = 0.08838834764831845f;  // 1/sqrt(128)
    const int ntiles = (qb * 64 + 64 + 31) >> 5;
    const int kk = tid >> 3, slot = tid & 7;
    const int vd = tid & 127, vhalf = tid >> 7;

    for (int kt = 0; kt < ntiles; ++kt) {
        const int kv0 = kt * 32;
        __syncthreads();
        {
            const size_t koff = (tb + kv0 + kk) * CQKV + CH + h * CHD + slot * 16;
            *(short8*)(&Ksh[kk][slot * 16])     = *(const short8*)(qh + koff);
            *(short8*)(&Ksh[kk][slot * 16 + 8]) = *(const short8*)(qh + koff + 8);
            *(short8*)(&Ksl[kk][slot * 16])     = *(const short8*)(ql + koff);
            *(short8*)(&Ksl[kk][slot * 16 + 8]) = *(const short8*)(ql + koff + 8);
            // V: column-strip loads (transposed write)
            const size_t voff = (tb + kv0 + vhalf * 16) * CQKV + 2 * CH + h * CHD + vd;
            unsigned short th[16], tl[16];
            #pragma unroll
            for (int j = 0; j < 16; j++) {
                th[j] = qh[voff + (size_t)j * CQKV];
                tl[j] = ql[voff + (size_t)j * CQKV];
            }
            #pragma unroll
            for (int p = 0; p < 2; p++) {
                *(ushort4v*)(&Vth[vd][vhalf * 16 + p * 8])     = *(ushort4v*)(&th[p * 8]);
                *(ushort4v*)(&Vth[vd][vhalf * 16 + p * 8 + 4]) = *(ushort4v*)(&th[p * 8 + 4]);
                *(ushort4v*)(&Vtl[vd][vhalf * 16 + p * 8])     = *(ushort4v*)(&tl[p * 8]);
                *(ushort4v*)(&Vtl[vd][vhalf * 16 + p * 8 + 4]) = *(ushort4v*)(&tl[p * 8 + 4]);
            }
        }
        __syncthreads();

        float4v st0 = (float4v){0.f,0.f,0.f,0.f}, st1 = st0;
        #pragma unroll
        for (int c = 0; c < 4; c++) {
            short8 kah = *(const short8*)(&Ksh[lr][c * 32 + lg * 8]);
            short8 kal = *(const short8*)(&Ksl[lr][c * 32 + lg * 8]);
            short8 kbh = *(const short8*)(&Ksh[16 + lr][c * 32 + lg * 8]);
            short8 kbl = *(const short8*)(&Ksl[16 + lr][c * 32 + lg * 8]);
            st0 = __builtin_amdgcn_mfma_f32_16x16x32_bf16(kal, qfh[c], st0, 0, 0, 0);
            st0 = __builtin_amdgcn_mfma_f32_16x16x32_bf16(kah, qfl[c], st0, 0, 0, 0);
            st0 = __builtin_amdgcn_mfma_f32_16x16x32_bf16(kah, qfh[c], st0, 0, 0, 0);
            st1 = __builtin_amdgcn_mfma_f32_16x16x32_bf16(kbl, qfh[c], st1, 0, 0, 0);
            st1 = __builtin_amdgcn_mfma_f32_16x16x32_bf16(kbh, qfl[c], st1, 0, 0, 0);
            st1 = __builtin_amdgcn_mfma_f32_16x16x32_bf16(kbh, qfh[c], st1, 0, 0, 0);
        }
        float pv[8]; float pmax = -1e30f;
        const int qg = q0 + lr;
        #pragma unroll
        for (int f = 0; f < 2; f++) {
            #pragma unroll
            for (int r = 0; r < 4; r++) {
                const int kg = kv0 + f * 16 + lg * 4 + r;
                const float s = (kg <= qg) ? ((f ? st1[r] : st0[r]) * scl) : -1e30f;
                pv[f * 4 + r] = s;
                pmax = fmaxf(pmax, s);
            }
        }
        pmax = fmaxf(pmax, __shfl_xor(pmax, 16));
        pmax = fmaxf(pmax, __shfl_xor(pmax, 32));
        const float mnew = fmaxf(m, pmax);
        const float alpha = __expf(m - mnew);
        float sum = 0.f;
        #pragma unroll
        for (int i = 0; i < 8; i++) { const float p = __expf(pv[i] - mnew); pv[i] = p; sum += p; }
        sum += __shfl_xor(sum, 16);
        sum += __shfl_xor(sum, 32);
        l = l * alpha + sum;
        m = mnew;
        #pragma unroll
        for (int d = 0; d < 8; d++) o[d] *= alpha;
        short8 pfh, pfl;
        unsigned short* pfhp = (unsigned short*)&pfh;
        unsigned short* pflp = (unsigned short*)&pfl;
        #pragma unroll
        for (int j = 0; j < 8; j++) {
            const int srcl = (((lg & 1) * 2 + (j >> 2)) << 4) | lr;
            const float a0 = __shfl(pv[j & 3], srcl);
            const float a1 = __shfl(pv[4 + (j & 3)], srcl);
            const float sel = (lg >= 2) ? a1 : a0;
            uint32 r = rnebits(sel);
            pfhp[j] = (unsigned short)(r >> 16);
            float d = sel - __uint_as_float(r & 0xffff0000u);
            pflp[j] = (unsigned short)(rnebits(d) >> 16);
        }
        #pragma unroll
        for (int dt = 0; dt < 8; dt++) {
            short8 vh = *(const short8*)(&Vth[dt * 16 + lr][lg * 8]);
            short8 vl = *(const short8*)(&Vtl[dt * 16 + lr][lg * 8]);
            o[dt] = __builtin_amdgcn_mfma_f32_16x16x32_bf16(vl, pfh, o[dt], 0, 0, 0);
            o[dt] = __builtin_amdgcn_mfma_f32_16x16x32_bf16(vh, pfl, o[dt], 0, 0, 0);
            o[dt] = __builtin_amdgcn_mfma_f32_16x16x32_bf16(vh, pfh, o[dt], 0, 0, 0);
        }
    }
    const float inv = 1.f / l;
    const size_t coff = (tb + q0 + lr) * CH + h * CHD + lg * 4;
    #pragma unroll
    for (int dt = 0; dt < 8; dt++) {
        ushort4v wh, wl;
        #pragma unroll
        for (int r = 0; r < 4; r++) {
            const float v = o[dt][r] * inv;
            uint32 rr = rnebits(v);
            wh[r] = (unsigned short)(rr >> 16);
            wl[r] = f2bf(v - __uint_as_float(rr & 0xffff0000u));
        }
        *(ushort4v*)(ch + coff + dt * 16) = wh;
        *(ushort4v*)(cl + coff + dt * 16) = wl;
    }
}

// ---------------- router: fp64 logits + top2 ----------------
__global__ __launch_bounds__(64) void router_k(const float* __restrict__ x,
                                               const float* __restrict__ wn,
                                               const float* __restrict__ rw,
                                               int* __restrict__ cnt, int* __restrict__ tok,
                                               float* __restrict__ gate) {
    const int t = blockIdx.x;
    const int lane = threadIdx.x;
    const float* xr = x + (size_t)t * CH;
    double ss = 0.0;
    double acc[8] = {0,0,0,0,0,0,0,0};
    for (int i = lane * 4; i < CH; i += 256) {
        float4 v = *(const float4*)(xr + i);
        float4 wv = *(const float4*)(wn + i);
        ss += (double)v.x*v.x + (double)v.y*v.y + (double)v.z*v.z + (double)v.w*v.w;
        float xs[4] = {v.x, v.y, v.z, v.w};
        float ws4[4] = {wv.x, wv.y, wv.z, wv.w};
        #pragma unroll
        for (int dd = 0; dd < 4; dd++) {
            const double xn = (double)xs[dd] * (double)ws4[dd];
            const float* rr = rw + (size_t)(i + dd) * CE;
            #pragma unroll
            for (int e2 = 0; e2 < 8; e2++) acc[e2] += xn * (double)rr[e2];
        }
    }
    #pragma unroll
    for (int o = 1; o < 64; o <<= 1) ss += __shfl_xor(ss, o);
    #pragma unroll
    for (int e2 = 0; e2 < 8; e2++) {
        #pragma unroll
        for (int o = 1; o < 64; o <<= 1) acc[e2] += __shfl_xor(acc[e2], o);
    }
    if (lane == 0) {
        const double scale = rsqrt(ss / (double)CH + 1e-5);
        int e0 = 0;
        #pragma unroll
        for (int e2 = 1; e2 < 8; e2++) if (acc[e2] > acc[e0]) e0 = e2;
        int e1 = (e0 == 0) ? 1 : 0;
        #pragma unroll
        for (int e2 = 0; e2 < 8; e2++) if (e2 != e0 && acc[e2] > acc[e1]) e1 = e2;
        const double dl = scale * (acc[e1] - acc[e0]);   // <= 0
        const double p1r = exp(dl);
        const float g0 = (float)(1.0 / (1.0 + p1r));
        const float g1 = (float)(p1r / (1.0 + p1r));
        int pos0 = atomicAdd(&cnt[e0], 1);
        tok[e0 * 4096 + pos0] = t; gate[e0 * 4096 + pos0] = g0;
        int pos1 = atomicAdd(&cnt[e1], 1);
        tok[e1 * 4096 + pos1] = t; gate[e1 * 4096 + pos1] = g1;
    }
}

__global__ void prefix_k(const int* __restrict__ cnt, int* __restrict__ pb) {
    if (threadIdx.x == 0 && blockIdx.x == 0) {
        int s = 0;
        for (int e = 0; e < CE; e++) { pb[e] = s; s += (cnt[e] + 127) & ~127; }
    }
}

// ---------------- launch ----------------
extern "C" void kernel_launch(void* const* d_in, const int* in_sizes, int n_in,
                              void* d_out, int out_size, void* d_ws, size_t ws_size,
                              hipStream_t stream) {
    (void)in_sizes; (void)n_in; (void)out_size; (void)ws_size;
    const float* hidden = (const float*)d_in[0];
    const int*   posids = (const int*)d_in[1];
    const float* rms1w  = (const float*)d_in[2];
    const float* rms2w  = (const float*)d_in[3];
    const float* qw     = (const float*)d_in[4];
    const float* kw     = (const float*)d_in[5];
    const float* vw     = (const float*)d_in[6];
    const float* ow     = (const float*)d_in[7];
    const float* rw     = (const float*)d_in[8];
    const float* w1     = (const float*)d_in[9];
    const float* w2     = (const float*)d_in[10];
    const float* w3     = (const float*)d_in[11];
    float* out = (float*)d_out;

    char* ws = (char*)d_ws;
    // [0,16.8M): h1h -> later h2 ; [16.8M,33.6M): h1l -> later tok/gate/cnt
    unsigned short* h1h = (unsigned short*)ws;
    unsigned short* h1l = (unsigned short*)(ws + 16777216);
    unsigned short* h2  = (unsigned short*)ws;
    int*   tok  = (int*)(ws + 16777216);
    float* gate = (float*)(ws + 16777216 + 131072);
    int*   cnt  = (int*)(ws + 16777216 + 262144);
    int*   pb   = cnt + 16;
    // [33.6M,134.2M): qkvh/qkvl -> later Hbuf
    unsigned short* qkvh = (unsigned short*)(ws + 33554432);
    unsigned short* qkvl = (unsigned short*)(ws + 83886080);
    unsigned short* Hbuf = (unsigned short*)(ws + 33554432);
    // [134.2M,167.8M): ctxh/ctxl
    unsigned short* ctxh = (unsigned short*)(ws + 134217728);
    unsigned short* ctxl = (unsigned short*)(ws + 150994944);
    // [167.8M,201.3M): res2 fp32 ; [201.3M,+1M): rope table
    float*  res2 = (float*)(ws + 167772160);
    float2* rtab = (float2*)(ws + 201326592);

    rope_tab_k<<<512, 256, 0, stream>>>(rtab);
    rmsnorm_k<0><<<CT, 256, 0, stream>>>(hidden, rms1w, h1h, h1l);
    pgemm_k<0><<<dim3(32, 48), 256, 0, stream>>>(h1h, h1l, CH, qw, kw, vw, CH, CH,
                                                 qkvh, qkvl, nullptr, CQKV, nullptr, nullptr);
    rope_k<<<16384, 256, 0, stream>>>(qkvh, qkvl, posids, rtab);
    attn_k<<<dim3(32, CNH, CB), 256, 0, stream>>>(qkvh, qkvl, ctxh, ctxl);
    pgemm_k<1><<<dim3(32, 16), 256, 0, stream>>>(ctxh, ctxl, CH, ow, nullptr, nullptr, CH, CH,
                                                 nullptr, nullptr, res2, CH, hidden, out);
    rmsnorm_k<1><<<CT, 256, 0, stream>>>(res2, rms2w, h2, nullptr);
    hipMemsetAsync(cnt, 0, 8 * sizeof(int), stream);
    router_k<<<CT, 64, 0, stream>>>(res2, rms2w, rw, cnt, tok, gate);
    prefix_k<<<1, 64, 0, stream>>>(cnt, pb);
    gemm_k<2><<<dim3(32, 32, 8), 256, 0, stream>>>(h2, CH, w1, w3, CI, CH, Hbuf, CI,
                                                   cnt, tok, gate, pb);
    gemm_k<3><<<dim3(32, 16, 8), 256, 0, stream>>>(Hbuf, CI, w2, nullptr, CH, CI, out, CH,
                                                   cnt, tok, gate, pb);
}

// Round 6
// 1511.464 us; speedup vs baseline: 1.9803x; 1.9803x over previous
//
#include <hip/hip_runtime.h>
#include <hip/hip_bf16.h>

// ---------------- constants ----------------
constexpr int CB   = 2;     // batch
constexpr int CS   = 2048;  // seq
constexpr int CH   = 2048;  // hidden
constexpr int CNH  = 16;    // heads
constexpr int CHD  = 128;   // head dim
constexpr int CE   = 8;     // experts
constexpr int CI   = 2048;  // ffn inner
constexpr int CT   = CB * CS;      // 4096 tokens
constexpr int CQKV = 3 * CH;       // 6144

typedef __attribute__((ext_vector_type(8))) short short8;
typedef __attribute__((ext_vector_type(4))) float float4v;
typedef __attribute__((ext_vector_type(4))) unsigned short ushort4v;
typedef unsigned int uint32;

__device__ __forceinline__ float bf2f(unsigned short u) {
    union { unsigned int i; float f; } x; x.i = ((unsigned int)u) << 16; return x.f;
}
__device__ __forceinline__ unsigned short f2bf(float f) {
    union { float f; unsigned int i; } x; x.f = f;
    unsigned int r = x.i + 0x7fffu + ((x.i >> 16) & 1u);
    return (unsigned short)(r >> 16);
}
__device__ __forceinline__ uint32 packpair(uint32 r0, uint32 r1) {
    return __builtin_amdgcn_perm(r1, r0, 0x07060302u);
}
__device__ __forceinline__ uint32 rnebits(float f) {
    uint32 u = __float_as_uint(f);
    return u + 0x7fffu + ((u >> 16) & 1u);
}
__device__ __forceinline__ void split2(float f0, float f1, uint32& h, uint32& l) {
    uint32 r0 = rnebits(f0), r1 = rnebits(f1);
    h = packpair(r0, r1);
    float d0 = f0 - __uint_as_float(r0 & 0xffff0000u);
    float d1 = f1 - __uint_as_float(r1 & 0xffff0000u);
    l = packpair(rnebits(d0), rnebits(d1));
}
__device__ __forceinline__ void rne16_store(const float* fv, unsigned short* dst) {
    uint32 h[8];
    #pragma unroll
    for (int p = 0; p < 8; p++) h[p] = packpair(rnebits(fv[2 * p]), rnebits(fv[2 * p + 1]));
    ((uint4*)dst)[0] = make_uint4(h[0], h[1], h[2], h[3]);
    ((uint4*)dst)[1] = make_uint4(h[4], h[5], h[6], h[7]);
}

// ---------------- RMSNorm. MODE 0: hi/lo split out. MODE 1: bf16 out ----------
template<int MODE>
__global__ __launch_bounds__(256) void rmsnorm_k(const float* __restrict__ x,
                                                 const float* __restrict__ w,
                                                 unsigned short* __restrict__ o1,
                                                 unsigned short* __restrict__ o2) {
    const int row = blockIdx.x;
    const float* xr = x + (size_t)row * CH;
    const int base = threadIdx.x * 8;
    float4 v0 = *(const float4*)(xr + base);
    float4 v1 = *(const float4*)(xr + base + 4);
    float ss = v0.x*v0.x + v0.y*v0.y + v0.z*v0.z + v0.w*v0.w
             + v1.x*v1.x + v1.y*v1.y + v1.z*v1.z + v1.w*v1.w;
    #pragma unroll
    for (int o = 1; o < 64; o <<= 1) ss += __shfl_xor(ss, o);
    __shared__ float ps[4];
    if ((threadIdx.x & 63) == 0) ps[threadIdx.x >> 6] = ss;
    __syncthreads();
    const float scale = rsqrtf((ps[0] + ps[1] + ps[2] + ps[3]) / (float)CH + 1e-5f);
    float4 w0 = *(const float4*)(w + base);
    float4 w1 = *(const float4*)(w + base + 4);
    float r[8] = {v0.x * scale * w0.x, v0.y * scale * w0.y, v0.z * scale * w0.z, v0.w * scale * w0.w,
                  v1.x * scale * w1.x, v1.y * scale * w1.y, v1.z * scale * w1.z, v1.w * scale * w1.w};
    if (MODE == 1) {
        rne16_store(r, o1 + (size_t)row * CH + base);
    } else {
        uint32 h[4], l[4];
        #pragma unroll
        for (int p = 0; p < 4; p++) split2(r[2 * p], r[2 * p + 1], h[p], l[p]);
        *(uint4*)(o1 + (size_t)row * CH + base) = make_uint4(h[0], h[1], h[2], h[3]);
        *(uint4*)(o2 + (size_t)row * CH + base) = make_uint4(l[0], l[1], l[2], l[3]);
    }
}

// ---------------- RoPE table (replicating np's fp32 rounding) ----
__global__ void rope_tab_k(float2* __restrict__ tab) {
    int i = blockIdx.x * 256 + threadIdx.x;   // 2048*64
    int p = i >> 6, j = i & 63;
    double inv = pow(10000.0, -(double)j / 64.0);
    float invf = (float)inv;
    float angf = (float)p * invf;
    double da = (double)angf;
    tab[i] = make_float2((float)cos(da), (float)sin(da));
}

// ---------------- RoPE (in-place on hi/lo split q,k) ----------------
__global__ __launch_bounds__(256) void rope_k(unsigned short* __restrict__ qh,
                                              unsigned short* __restrict__ ql,
                                              const int* __restrict__ pos,
                                              const float2* __restrict__ tab) {
    int i = blockIdx.x * 256 + threadIdx.x;  // CT*16*64
    if (i >= CT * CNH * 64) return;
    int t = i >> 10, hj = i & 1023, hh = hj >> 6, j = hj & 63;
    float2 cs = tab[(size_t)pos[t] * 64 + j];
    unsigned short* qhp = qh + (size_t)t * CQKV + hh * CHD;
    unsigned short* qlp = ql + (size_t)t * CQKV + hh * CHD;
    #pragma unroll
    for (int s = 0; s < 2; s++) {
        unsigned short* hp = qhp + s * CH;   // q then k
        unsigned short* lp = qlp + s * CH;
        float x1 = bf2f(hp[j]) + bf2f(lp[j]);
        float x2 = bf2f(hp[j + 64]) + bf2f(lp[j + 64]);
        float y1 = x1 * cs.x - x2 * cs.y;
        float y2 = x2 * cs.x + x1 * cs.y;
        uint32 r1 = rnebits(y1), r2 = rnebits(y2);
        hp[j]      = (unsigned short)(r1 >> 16);
        hp[j + 64] = (unsigned short)(r2 >> 16);
        lp[j]      = f2bf(y1 - __uint_as_float(r1 & 0xffff0000u));
        lp[j + 64] = f2bf(y2 - __uint_as_float(r2 & 0xffff0000u));
    }
}

// ---------------- weight transpose+convert: src[e][K][N] f32 -> dst[e][NMAT*n+s][K] bf16
template<int NMAT>
__global__ __launch_bounds__(256) void conv_k(const float* __restrict__ S0,
                                              const float* __restrict__ S1,
                                              unsigned short* __restrict__ D) {
    __shared__ float t[64][65];
    const int n0 = blockIdx.x * 64, k0 = blockIdx.y * 64, e = blockIdx.z;
    const size_t esrc = (size_t)e * 2048 * 2048;
    const int cc = threadIdx.x & 63, r4 = threadIdx.x >> 6;
    const int nl = threadIdx.x >> 2, q = threadIdx.x & 3;
    #pragma unroll
    for (int s = 0; s < NMAT; s++) {
        const float* S = s ? S1 : S0;
        __syncthreads();
        #pragma unroll
        for (int j = 0; j < 16; j++) {
            const int row = j * 4 + r4;
            t[cc][row] = S[esrc + (size_t)(k0 + row) * 2048 + n0 + cc];
        }
        __syncthreads();
        const int orow = (NMAT == 2) ? (2 * (n0 + nl) + s) : (n0 + nl);
        unsigned short* dp = D + (size_t)e * (NMAT * 2048) * 2048 + (size_t)orow * 2048 + k0 + q * 16;
        float fv[16];
        #pragma unroll
        for (int j = 0; j < 16; j++) fv[j] = t[nl][q * 16 + j];
        rne16_store(fv, dp);
    }
}

// ---------------- precise split-bf16 GEMM: A split-bf16, B fp32 ----------------
// Register-prefetch pipelined. Grid: x = mt (row tiles), y = nt (col tiles).
// MODE 0: QKV — B from (q_w,k_w,v_w) by nt>>4, out split hi/lo bf16
// MODE 1: C f32 = A@B + resid, dual-store C2
template<int MODE>
__global__ __launch_bounds__(256) void pgemm_k(
    const unsigned short* __restrict__ Ahg, const unsigned short* __restrict__ Alg, int lda,
    const float* __restrict__ B0, const float* __restrict__ B1, const float* __restrict__ B2,
    int ldb, int K,
    unsigned short* __restrict__ Ch, unsigned short* __restrict__ Cl,
    float* __restrict__ Cf, int ldc,
    const float* __restrict__ resid, float* __restrict__ C2) {
    __shared__ unsigned short Ah[128][40], Al[128][40];
    __shared__ unsigned short Bh[128][40], Bl[128][40];
    const int mt = blockIdx.x, nt = blockIdx.y, tid = threadIdx.x;
    const int m0 = mt * 128;
    const int arow = tid >> 1, acol = tid & 1;
    const unsigned short* ah_src = Ahg + (size_t)(m0 + arow) * lda + acol * 16;
    const unsigned short* al_src = Alg + (size_t)(m0 + arow) * lda + acol * 16;
    const float* src = B0; int col0 = nt * 128;
    if (MODE == 0) { int w = nt >> 4; src = (w == 0) ? B0 : ((w == 1) ? B1 : B2); col0 = (nt & 15) * 128; }
    const int bc_ = tid & 127, bhalf = tid >> 7;
    const float* bcol = src + col0 + bc_;   // column strip, row stride = ldb
    const int lane = tid & 63, lr = lane & 15, lg = lane >> 4;
    const int wr = (tid >> 7) & 1, wc = (tid >> 6) & 1;

    float4v acc[4][4];
    #pragma unroll
    for (int m = 0; m < 4; m++)
        #pragma unroll
        for (int n = 0; n < 4; n++) acc[m][n] = (float4v){0.f, 0.f, 0.f, 0.f};

    // prefetch k0 = 0
    short8 pah0 = *(const short8*)(ah_src);
    short8 pah1 = *(const short8*)(ah_src + 8);
    short8 pal0 = *(const short8*)(al_src);
    short8 pal1 = *(const short8*)(al_src + 8);
    float bv[16];
    {
        const float* bp = bcol + (size_t)(bhalf * 16) * ldb;
        #pragma unroll
        for (int j = 0; j < 16; j++) bv[j] = bp[(size_t)j * ldb];
    }

    for (int k0 = 0; k0 < K; k0 += 32) {
        __syncthreads();
        *(short8*)(&Ah[arow][acol * 16]) = pah0;
        *(short8*)(&Ah[arow][acol * 16 + 8]) = pah1;
        *(short8*)(&Al[arow][acol * 16]) = pal0;
        *(short8*)(&Al[arow][acol * 16 + 8]) = pal1;
        {   // split B regs -> LDS
            uint32 h[8], l[8];
            #pragma unroll
            for (int p = 0; p < 8; p++) split2(bv[2 * p], bv[2 * p + 1], h[p], l[p]);
            ((uint4*)&Bh[bc_][bhalf * 16])[0] = make_uint4(h[0], h[1], h[2], h[3]);
            ((uint4*)&Bh[bc_][bhalf * 16])[1] = make_uint4(h[4], h[5], h[6], h[7]);
            ((uint4*)&Bl[bc_][bhalf * 16])[0] = make_uint4(l[0], l[1], l[2], l[3]);
            ((uint4*)&Bl[bc_][bhalf * 16])[1] = make_uint4(l[4], l[5], l[6], l[7]);
        }
        if (k0 + 32 < K) {   // prefetch next tile (latency hides under MFMA phase)
            pah0 = *(const short8*)(ah_src + k0 + 32);
            pah1 = *(const short8*)(ah_src + k0 + 40);
            pal0 = *(const short8*)(al_src + k0 + 32);
            pal1 = *(const short8*)(al_src + k0 + 40);
            const float* bp = bcol + (size_t)(k0 + 32 + bhalf * 16) * ldb;
            #pragma unroll
            for (int j = 0; j < 16; j++) bv[j] = bp[(size_t)j * ldb];
        }
        __syncthreads();
        short8 fah[4], fal[4], fbh[4], fbl[4];
        #pragma unroll
        for (int m = 0; m < 4; m++) {
            fah[m] = *(const short8*)(&Ah[wr * 64 + m * 16 + lr][lg * 8]);
            fal[m] = *(const short8*)(&Al[wr * 64 + m * 16 + lr][lg * 8]);
        }
        #pragma unroll
        for (int n = 0; n < 4; n++) {
            fbh[n] = *(const short8*)(&Bh[wc * 64 + n * 16 + lr][lg * 8]);
            fbl[n] = *(const short8*)(&Bl[wc * 64 + n * 16 + lr][lg * 8]);
        }
        #pragma unroll
        for (int n = 0; n < 4; n++)
            #pragma unroll
            for (int m = 0; m < 4; m++) {
                acc[m][n] = __builtin_amdgcn_mfma_f32_16x16x32_bf16(fal[m], fbh[n], acc[m][n], 0, 0, 0);
                acc[m][n] = __builtin_amdgcn_mfma_f32_16x16x32_bf16(fah[m], fbl[n], acc[m][n], 0, 0, 0);
                acc[m][n] = __builtin_amdgcn_mfma_f32_16x16x32_bf16(fah[m], fbh[n], acc[m][n], 0, 0, 0);
            }
    }
    #pragma unroll
    for (int m = 0; m < 4; m++) {
        const int rb = wr * 64 + m * 16 + lg * 4;
        #pragma unroll
        for (int n = 0; n < 4; n++) {
            const int ccol = nt * 128 + wc * 64 + n * 16 + lr;
            #pragma unroll
            for (int r = 0; r < 4; r++) {
                const size_t idx = (size_t)(m0 + rb + r) * ldc + ccol;
                if (MODE == 1) {
                    const float v = acc[m][n][r] + resid[idx];
                    Cf[idx] = v;
                    C2[idx] = v;
                } else {
                    const float v = acc[m][n][r];
                    uint32 rr = rnebits(v);
                    Ch[idx] = (unsigned short)(rr >> 16);
                    Cl[idx] = f2bf(v - __uint_as_float(rr & 0xffff0000u));
                }
            }
        }
    }
}

// ---------------- MoE GEMM: A bf16 row-major, B bf16 pre-transposed [Ne][K] ----
// Grid: x = nt (so same-panel blocks land on the same XCD), y = mt, z = e.
// MODE 2: up: A gathered by token list, B = wt13 interleaved, SwiGLU -> bf16 H
// MODE 3: down: A = Hbuf rows, epilogue gate*val atomicAdd into out
template<int MODE>
__global__ __launch_bounds__(256) void gemm_k(
    const unsigned short* __restrict__ A, int lda,
    const unsigned short* __restrict__ Bt, int K, int Ne,
    void* __restrict__ Cp, int ldc,
    const int* __restrict__ cnt, const int* __restrict__ tokl,
    const float* __restrict__ gatel, const int* __restrict__ pb) {
    __shared__ unsigned short As[128][40];
    __shared__ unsigned short Bs[128][40];
    const int nt = blockIdx.x, mt = blockIdx.y, e = blockIdx.z;
    const int m0 = mt * 128;
    const int c = cnt[e];
    if (m0 >= c) return;
    const int valid = (c - m0 < 128) ? (c - m0) : 128;
    const int tid = threadIdx.x;
    const int srow = tid >> 1, shalf = tid & 1;
    size_t gr;
    if (MODE == 2) {
        const int idx = m0 + (srow < valid ? srow : valid - 1);
        gr = (size_t)tokl[e * 4096 + idx];
    } else {
        const int rr = m0 + srow;
        gr = (size_t)(pb[e] + (rr < c ? rr : c - 1));
    }
    const unsigned short* a_src = A + gr * (size_t)lda + shalf * 16;
    const unsigned short* b_src = Bt + (size_t)e * Ne * K + (size_t)(nt * 128 + srow) * K + shalf * 16;
    const int lane = tid & 63, lr = lane & 15, lg = lane >> 4;
    const int wr = (tid >> 7) & 1, wc = (tid >> 6) & 1;

    float4v acc[4][4];
    #pragma unroll
    for (int m = 0; m < 4; m++)
        #pragma unroll
        for (int n = 0; n < 4; n++) acc[m][n] = (float4v){0.f, 0.f, 0.f, 0.f};

    short8 ra0 = *(const short8*)(a_src);
    short8 ra1 = *(const short8*)(a_src + 8);
    short8 rb0 = *(const short8*)(b_src);
    short8 rb1 = *(const short8*)(b_src + 8);

    for (int k0 = 0; k0 < K; k0 += 32) {
        __syncthreads();
        *(short8*)(&As[srow][shalf * 16])     = ra0;
        *(short8*)(&As[srow][shalf * 16 + 8]) = ra1;
        *(short8*)(&Bs[srow][shalf * 16])     = rb0;
        *(short8*)(&Bs[srow][shalf * 16 + 8]) = rb1;
        if (k0 + 32 < K) {
            ra0 = *(const short8*)(a_src + k0 + 32);
            ra1 = *(const short8*)(a_src + k0 + 40);
            rb0 = *(const short8*)(b_src + k0 + 32);
            rb1 = *(const short8*)(b_src + k0 + 40);
        }
        __syncthreads();
        short8 af[4], bf[4];
        #pragma unroll
        for (int m = 0; m < 4; m++) af[m] = *(const short8*)(&As[wr * 64 + m * 16 + lr][lg * 8]);
        #pragma unroll
        for (int n = 0; n < 4; n++) bf[n] = *(const short8*)(&Bs[wc * 64 + n * 16 + lr][lg * 8]);
        #pragma unroll
        for (int n = 0; n < 4; n++)
            #pragma unroll
            for (int m = 0; m < 4; m++)
                acc[m][n] = __builtin_amdgcn_mfma_f32_16x16x32_bf16(af[m], bf[n], acc[m][n], 0, 0, 0);
    }

    #pragma unroll
    for (int m = 0; m < 4; m++) {
        const int rb = wr * 64 + m * 16 + lg * 4;
        #pragma unroll
        for (int n = 0; n < 4; n++) {
            const int col = nt * 128 + wc * 64 + n * 16 + lr;
            #pragma unroll
            for (int r = 0; r < 4; r++) {
                const int row = rb + r;
                const float v = acc[m][n][r];
                if (MODE == 2) {
                    const float other = __shfl_xor(v, 1);
                    if (!(lr & 1) && row < valid) {
                        const float g1 = v, g3 = other;
                        const float hsw = (g1 / (1.f + __expf(-g1))) * g3;
                        ((unsigned short*)Cp)[(size_t)(pb[e] + m0 + row) * ldc + (col >> 1)] = f2bf(hsw);
                    }
                } else {
                    if (row < valid) {
                        const int t = tokl[e * 4096 + m0 + row];
                        const float g = gatel[e * 4096 + m0 + row];
                        atomicAdd(((float*)Cp) + (size_t)t * ldc + col, v * g);
                    }
                }
            }
        }
    }
}

// ---------------- flash attention, split-bf16 in/out ----------
__global__ __launch_bounds__(256) void attn_k(const unsigned short* __restrict__ qh,
                                              const unsigned short* __restrict__ ql,
                                              unsigned short* __restrict__ ch,
                                              unsigned short* __restrict__ cl) {
    __shared__ unsigned short Ksh[32][136], Ksl[32][136];
    __shared__ unsigned short Vth[128][40], Vtl[128][40];
    const int qb = blockIdx.x;
    const int h  = blockIdx.y;
    const int b  = blockIdx.z;
    const int tid = threadIdx.x;
    const int wave = tid >> 6, lane = tid & 63, lr = lane & 15, lg = lane >> 4;
    const size_t tb = (size_t)b * CS;
    const int q0 = qb * 64 + wave * 16;

    short8 qfh[4], qfl[4];
    {
        const size_t off = (tb + q0 + lr) * CQKV + h * CHD;
        #pragma unroll
        for (int c = 0; c < 4; c++) {
            qfh[c] = *(const short8*)(qh + off + c * 32 + lg * 8);
            qfl[c] = *(const short8*)(ql + off + c * 32 + lg * 8);
        }
    }
    float4v o[8];
    #pragma unroll
    for (int d = 0; d < 8; d++) o[d] = (float4v){0.f, 0.f, 0.f, 0.f};
    float m = -1e30f, l = 0.f;
    const float scl = 0.08838834764831845f;  // 1/sqrt(128)
    const int ntiles = (qb * 64 + 64 + 31) >> 5;
    const int kk = tid >> 3, slot = tid & 7;
    const int vd = tid & 127, vhalf = tid >> 7;

    for (int kt = 0; kt < ntiles; ++kt) {
        const int kv0 = kt * 32;
        __syncthreads();
        {
            const size_t koff = (tb + kv0 + kk) * CQKV + CH + h * CHD + slot * 16;
            *(short8*)(&Ksh[kk][slot * 16])     = *(const short8*)(qh + koff);
            *(short8*)(&Ksh[kk][slot * 16 + 8]) = *(const short8*)(qh + koff + 8);
            *(short8*)(&Ksl[kk][slot * 16])     = *(const short8*)(ql + koff);
            *(short8*)(&Ksl[kk][slot * 16 + 8]) = *(const short8*)(ql + koff + 8);
            // V: column-strip loads (transposed write)
            const size_t voff = (tb + kv0 + vhalf * 16) * CQKV + 2 * CH + h * CHD + vd;
            unsigned short th[16], tl[16];
            #pragma unroll
            for (int j = 0; j < 16; j++) {
                th[j] = qh[voff + (size_t)j * CQKV];
                tl[j] = ql[voff + (size_t)j * CQKV];
            }
            #pragma unroll
            for (int p = 0; p < 2; p++) {
                *(ushort4v*)(&Vth[vd][vhalf * 16 + p * 8])     = *(ushort4v*)(&th[p * 8]);
                *(ushort4v*)(&Vth[vd][vhalf * 16 + p * 8 + 4]) = *(ushort4v*)(&th[p * 8 + 4]);
                *(ushort4v*)(&Vtl[vd][vhalf * 16 + p * 8])     = *(ushort4v*)(&tl[p * 8]);
                *(ushort4v*)(&Vtl[vd][vhalf * 16 + p * 8 + 4]) = *(ushort4v*)(&tl[p * 8 + 4]);
            }
        }
        __syncthreads();

        float4v st0 = (float4v){0.f,0.f,0.f,0.f}, st1 = st0;
        #pragma unroll
        for (int c = 0; c < 4; c++) {
            short8 kah = *(const short8*)(&Ksh[lr][c * 32 + lg * 8]);
            short8 kal = *(const short8*)(&Ksl[lr][c * 32 + lg * 8]);
            short8 kbh = *(const short8*)(&Ksh[16 + lr][c * 32 + lg * 8]);
            short8 kbl = *(const short8*)(&Ksl[16 + lr][c * 32 + lg * 8]);
            st0 = __builtin_amdgcn_mfma_f32_16x16x32_bf16(kal, qfh[c], st0, 0, 0, 0);
            st0 = __builtin_amdgcn_mfma_f32_16x16x32_bf16(kah, qfl[c], st0, 0, 0, 0);
            st0 = __builtin_amdgcn_mfma_f32_16x16x32_bf16(kah, qfh[c], st0, 0, 0, 0);
            st1 = __builtin_amdgcn_mfma_f32_16x16x32_bf16(kbl, qfh[c], st1, 0, 0, 0);
            st1 = __builtin_amdgcn_mfma_f32_16x16x32_bf16(kbh, qfl[c], st1, 0, 0, 0);
            st1 = __builtin_amdgcn_mfma_f32_16x16x32_bf16(kbh, qfh[c], st1, 0, 0, 0);
        }
        float pv[8]; float pmax = -1e30f;
        const int qg = q0 + lr;
        #pragma unroll
        for (int f = 0; f < 2; f++) {
            #pragma unroll
            for (int r = 0; r < 4; r++) {
                const int kg = kv0 + f * 16 + lg * 4 + r;
                const float s = (kg <= qg) ? ((f ? st1[r] : st0[r]) * scl) : -1e30f;
                pv[f * 4 + r] = s;
                pmax = fmaxf(pmax, s);
            }
        }
        pmax = fmaxf(pmax, __shfl_xor(pmax, 16));
        pmax = fmaxf(pmax, __shfl_xor(pmax, 32));
        const float mnew = fmaxf(m, pmax);
        const float alpha = __expf(m - mnew);
        float sum = 0.f;
        #pragma unroll
        for (int i = 0; i < 8; i++) { const float p = __expf(pv[i] - mnew); pv[i] = p; sum += p; }
        sum += __shfl_xor(sum, 16);
        sum += __shfl_xor(sum, 32);
        l = l * alpha + sum;
        m = mnew;
        #pragma unroll
        for (int d = 0; d < 8; d++) o[d] *= alpha;
        short8 pfh, pfl;
        unsigned short* pfhp = (unsigned short*)&pfh;
        unsigned short* pflp = (unsigned short*)&pfl;
        #pragma unroll
        for (int j = 0; j < 8; j++) {
            const int srcl = (((lg & 1) * 2 + (j >> 2)) << 4) | lr;
            const float a0 = __shfl(pv[j & 3], srcl);
            const float a1 = __shfl(pv[4 + (j & 3)], srcl);
            const float sel = (lg >= 2) ? a1 : a0;
            uint32 r = rnebits(sel);
            pfhp[j] = (unsigned short)(r >> 16);
            float d = sel - __uint_as_float(r & 0xffff0000u);
            pflp[j] = (unsigned short)(rnebits(d) >> 16);
        }
        #pragma unroll
        for (int dt = 0; dt < 8; dt++) {
            short8 vh = *(const short8*)(&Vth[dt * 16 + lr][lg * 8]);
            short8 vl = *(const short8*)(&Vtl[dt * 16 + lr][lg * 8]);
            o[dt] = __builtin_amdgcn_mfma_f32_16x16x32_bf16(vl, pfh, o[dt], 0, 0, 0);
            o[dt] = __builtin_amdgcn_mfma_f32_16x16x32_bf16(vh, pfl, o[dt], 0, 0, 0);
            o[dt] = __builtin_amdgcn_mfma_f32_16x16x32_bf16(vh, pfh, o[dt], 0, 0, 0);
        }
    }
    const float inv = 1.f / l;
    const size_t coff = (tb + q0 + lr) * CH + h * CHD + lg * 4;
    #pragma unroll
    for (int dt = 0; dt < 8; dt++) {
        ushort4v wh, wl;
        #pragma unroll
        for (int r = 0; r < 4; r++) {
            const float v = o[dt][r] * inv;
            uint32 rr = rnebits(v);
            wh[r] = (unsigned short)(rr >> 16);
            wl[r] = f2bf(v - __uint_as_float(rr & 0xffff0000u));
        }
        *(ushort4v*)(ch + coff + dt * 16) = wh;
        *(ushort4v*)(cl + coff + dt * 16) = wl;
    }
}

// ---------------- router: fp64 logits + top2 ----------------
__global__ __launch_bounds__(64) void router_k(const float* __restrict__ x,
                                               const float* __restrict__ wn,
                                               const float* __restrict__ rw,
                                               int* __restrict__ cnt, int* __restrict__ tok,
                                               float* __restrict__ gate) {
    const int t = blockIdx.x;
    const int lane = threadIdx.x;
    const float* xr = x + (size_t)t * CH;
    double ss = 0.0;
    double acc[8] = {0,0,0,0,0,0,0,0};
    for (int i = lane * 4; i < CH; i += 256) {
        float4 v = *(const float4*)(xr + i);
        float4 wv = *(const float4*)(wn + i);
        ss += (double)v.x*v.x + (double)v.y*v.y + (double)v.z*v.z + (double)v.w*v.w;
        float xs[4] = {v.x, v.y, v.z, v.w};
        float ws4[4] = {wv.x, wv.y, wv.z, wv.w};
        #pragma unroll
        for (int dd = 0; dd < 4; dd++) {
            const double xn = (double)xs[dd] * (double)ws4[dd];
            const float* rr = rw + (size_t)(i + dd) * CE;
            #pragma unroll
            for (int e2 = 0; e2 < 8; e2++) acc[e2] += xn * (double)rr[e2];
        }
    }
    #pragma unroll
    for (int o = 1; o < 64; o <<= 1) ss += __shfl_xor(ss, o);
    #pragma unroll
    for (int e2 = 0; e2 < 8; e2++) {
        #pragma unroll
        for (int o = 1; o < 64; o <<= 1) acc[e2] += __shfl_xor(acc[e2], o);
    }
    if (lane == 0) {
        const double scale = rsqrt(ss / (double)CH + 1e-5);
        int e0 = 0;
        #pragma unroll
        for (int e2 = 1; e2 < 8; e2++) if (acc[e2] > acc[e0]) e0 = e2;
        int e1 = (e0 == 0) ? 1 : 0;
        #pragma unroll
        for (int e2 = 0; e2 < 8; e2++) if (e2 != e0 && acc[e2] > acc[e1]) e1 = e2;
        const double dl = scale * (acc[e1] - acc[e0]);   // <= 0
        const double p1r = exp(dl);
        const float g0 = (float)(1.0 / (1.0 + p1r));
        const float g1 = (float)(p1r / (1.0 + p1r));
        int pos0 = atomicAdd(&cnt[e0], 1);
        tok[e0 * 4096 + pos0] = t; gate[e0 * 4096 + pos0] = g0;
        int pos1 = atomicAdd(&cnt[e1], 1);
        tok[e1 * 4096 + pos1] = t; gate[e1 * 4096 + pos1] = g1;
    }
}

__global__ void prefix_k(const int* __restrict__ cnt, int* __restrict__ pb) {
    if (threadIdx.x == 0 && blockIdx.x == 0) {
        int s = 0;
        for (int e = 0; e < CE; e++) { pb[e] = s; s += cnt[e]; }
    }
}

// ---------------- launch ----------------
extern "C" void kernel_launch(void* const* d_in, const int* in_sizes, int n_in,
                              void* d_out, int out_size, void* d_ws, size_t ws_size,
                              hipStream_t stream) {
    (void)in_sizes; (void)n_in; (void)out_size; (void)ws_size;
    const float* hidden = (const float*)d_in[0];
    const int*   posids = (const int*)d_in[1];
    const float* rms1w  = (const float*)d_in[2];
    const float* rms2w  = (const float*)d_in[3];
    const float* qw     = (const float*)d_in[4];
    const float* kw     = (const float*)d_in[5];
    const float* vw     = (const float*)d_in[6];
    const float* ow     = (const float*)d_in[7];
    const float* rw     = (const float*)d_in[8];
    const float* w1     = (const float*)d_in[9];
    const float* w2     = (const float*)d_in[10];
    const float* w3     = (const float*)d_in[11];
    float* out = (float*)d_out;

    char* ws = (char*)d_ws;
    // lifetimes (MB):
    // [0,16.8): h1h -> h2            [16.8,33.6): h1l -> tok/gate/cnt/pb
    // [33.6,134.2): qkvh+qkvl (dead after attn)
    // [33.6,167.8): wt13 bf16 (after O-proj)  -> then wt2 at [33.6,100.7) after up-GEMM
    // [134.2,167.8): ctx split (dead after O-proj)
    // [167.8,201.4): res2 f32 -> Hbuf bf16 (8192x2048, unpadded)
    // [201.4,202.4): rope table
    unsigned short* h1h = (unsigned short*)ws;
    unsigned short* h1l = (unsigned short*)(ws + 16777216);
    unsigned short* h2  = (unsigned short*)ws;
    int*   tok  = (int*)(ws + 16777216);
    float* gate = (float*)(ws + 16777216 + 131072);
    int*   cnt  = (int*)(ws + 16777216 + 262144);
    int*   pb   = cnt + 16;
    unsigned short* qkvh = (unsigned short*)(ws + 33554432);
    unsigned short* qkvl = (unsigned short*)(ws + 83886080);
    unsigned short* wt13 = (unsigned short*)(ws + 33554432);
    unsigned short* wt2  = (unsigned short*)(ws + 33554432);
    unsigned short* ctxh = (unsigned short*)(ws + 134217728);
    unsigned short* ctxl = (unsigned short*)(ws + 150994944);
    float*          res2 = (float*)(ws + 167772160);
    unsigned short* Hbuf = (unsigned short*)(ws + 167772160);
    float2*         rtab = (float2*)(ws + 201326592);

    rope_tab_k<<<512, 256, 0, stream>>>(rtab);
    rmsnorm_k<0><<<CT, 256, 0, stream>>>(hidden, rms1w, h1h, h1l);
    pgemm_k<0><<<dim3(32, 48), 256, 0, stream>>>(h1h, h1l, CH, qw, kw, vw, CH, CH,
                                                 qkvh, qkvl, nullptr, CQKV, nullptr, nullptr);
    rope_k<<<16384, 256, 0, stream>>>(qkvh, qkvl, posids, rtab);
    attn_k<<<dim3(32, CNH, CB), 256, 0, stream>>>(qkvh, qkvl, ctxh, ctxl);
    pgemm_k<1><<<dim3(32, 16), 256, 0, stream>>>(ctxh, ctxl, CH, ow, nullptr, nullptr, CH, CH,
                                                 nullptr, nullptr, res2, CH, hidden, out);
    rmsnorm_k<1><<<CT, 256, 0, stream>>>(res2, rms2w, h2, nullptr);
    hipMemsetAsync(cnt, 0, 8 * sizeof(int), stream);
    router_k<<<CT, 64, 0, stream>>>(res2, rms2w, rw, cnt, tok, gate);
    prefix_k<<<1, 64, 0, stream>>>(cnt, pb);
    // convert w1,w3 -> wt13 (interleaved, transposed, bf16); overlays dead qkv+ctx
    conv_k<2><<<dim3(32, 32, CE), 256, 0, stream>>>(w1, w3, wt13);
    gemm_k<2><<<dim3(32, 32, CE), 256, 0, stream>>>(h2, CH, wt13, CH, 2 * CI, Hbuf, CI,
                                                    cnt, tok, gate, pb);
    // convert w2 -> wt2 (transposed, bf16); overlays dead wt13
    conv_k<1><<<dim3(32, 32, CE), 256, 0, stream>>>(w2, nullptr, wt2);
    gemm_k<3><<<dim3(16, 32, CE), 256, 0, stream>>>(Hbuf, CI, wt2, CI, CH, out, CH,
                                                    cnt, tok, gate, pb);
}